// Round 3
// baseline (227.857 us; speedup 1.0000x reference)
//
#include <hip/hip_runtime.h>

#define TAU 0.2f
#define VTH 0.3f

#define PPB 256   // pixels per block (= blockDim.x)
#define PADF 12   // floats per pixel slot in LDS: 8 data + 4 pad.
                  // 12 floats = 3 f4-columns, coprime with 8 -> even LDS bank
                  // columns for both linear-scatter and strided-read phases,
                  // and every slot stays 16B-aligned so b128 LDS ops are used.

typedef float v4f __attribute__((ext_vector_type(4)));  // native clang vector:
// required by __builtin_nontemporal_store (HIP_vector_type float4 is rejected).

// x: [B, C, H, W, T] fp32, T=8 innermost/contiguous. One thread per pixel.
// All global traffic is lane-contiguous 16B; the pixel-major <-> lane-major
// transpose happens in LDS.
__global__ __launch_bounds__(256) void LIFSpike_73864847556979_kernel(
    const float* __restrict__ x, float* __restrict__ out) {
    __shared__ float lds[PPB * PADF];
    const int t = threadIdx.x;
    const size_t base_f4 = (size_t)blockIdx.x * (PPB * 2);

    const v4f* __restrict__ xin = (const v4f*)x + base_f4;
    v4f* __restrict__ xout = (v4f*)out + base_f4;

    // Phase 1: fully-coalesced loads; scatter into pixel-padded LDS layout.
    v4f a = xin[t];
    v4f b = xin[t + 256];
    const int j0 = t, j1 = t + 256;  // linear f4 indices within block
    *(v4f*)&lds[(j0 >> 1) * PADF + (j0 & 1) * 4] = a;
    *(v4f*)&lds[(j1 >> 1) * PADF + (j1 & 1) * 4] = b;
    __syncthreads();

    // Phase 2: each thread reads its own pixel's 8 timesteps, scans in regs.
    v4f lo = *(const v4f*)&lds[t * PADF];
    v4f hi = *(const v4f*)&lds[t * PADF + 4];
    float v[8] = {lo.x, lo.y, lo.z, lo.w, hi.x, hi.y, hi.z, hi.w};
    float r[8];
    float u = 0.0f, o = 0.0f;
#pragma unroll
    for (int k = 0; k < 8; ++k) {
        u = TAU * u * (1.0f - o) + v[k];
        o = (u > VTH) ? 1.0f : 0.0f;
        r[k] = o;
    }
    // Thread t is the only reader/writer of slot t in this phase -> no barrier
    // needed before the write.
    *(v4f*)&lds[t * PADF] = (v4f){r[0], r[1], r[2], r[3]};
    *(v4f*)&lds[t * PADF + 4] = (v4f){r[4], r[5], r[6], r[7]};
    __syncthreads();

    // Phase 3: gather in linear order; fully-coalesced nontemporal stores
    // (output is write-once, never re-read -> keep it out of L3 so x stays
    // resident).
    v4f c = *(const v4f*)&lds[(j0 >> 1) * PADF + (j0 & 1) * 4];
    v4f d = *(const v4f*)&lds[(j1 >> 1) * PADF + (j1 & 1) * 4];
    __builtin_nontemporal_store(c, &xout[t]);
    __builtin_nontemporal_store(d, &xout[t + 256]);
}

extern "C" void kernel_launch(void* const* d_in, const int* in_sizes, int n_in,
                              void* d_out, int out_size, void* d_ws, size_t ws_size,
                              hipStream_t stream) {
    const float* x = (const float*)d_in[0];
    float* out = (float*)d_out;
    int n_pixels = in_sizes[0] / 8;          // T = 8
    int grid = n_pixels / PPB;               // 4194304 / 256 = 16384, exact
    LIFSpike_73864847556979_kernel<<<grid, PPB, 0, stream>>>(x, out);
}